// Round 1
// 149.342 us; speedup vs baseline: 1.1183x; 1.1183x over previous
//
#include <hip/hip_runtime.h>

typedef _Float16 f16;
typedef _Float16 f16x2 __attribute__((ext_vector_type(2)));
typedef _Float16 f16x4 __attribute__((ext_vector_type(4)));
typedef _Float16 f16x8 __attribute__((ext_vector_type(8)));
typedef float    f32x4 __attribute__((ext_vector_type(4)));

// Geometry:
//   x:   (4,128,64,64) f32     p5: (128,21,64,64) f32
//   p6:  (128,21,128)  f32     out:(4,128,64,64)  f32
// Workspace:
//   xk  [3][4][128][82][64] f16 = x*(1/8), pre-shifted per kc, zero-padded rows
//   t6B [4][21][4][8][4][16][8] f16 = p6 * t3, MFMA-fragment-packed:
//        idx(n,rk,g,dblk,quad,l16,i) -> value t6[n][c=g*32+quad*8+i][rk][d=dblk*16+l16]
//        so outp's B-fragment load is base + lane*16B (fully coalesced 1KB/wave)
//   t3p [8][4][11][128][128] f16 = split-K Gram partials, rki 0..10 ONLY
//        (t3[c,rk,d] = t3[d,20-rk,c] exactly — lag symmetry; ep mirrors rk>=11)
//   t8p [4][4][64][128][64]  f16 = split-K out partials (g,n,h,d,w), ALIASES t3p
#define XROWS 82
#define XSTR  (XROWS * 64)
#define XK_ELEMS (3u * 4u * 128u * (unsigned)XSTR)
static const size_t T6T_OFF   = (size_t)XK_ELEMS * 2;                 // 16.12 MB
static const size_t T6T_BYTES = (size_t)4 * 128 * 2688 * 2;           // 2.75 MB
static const size_t T3P_OFF   = T6T_OFF + T6T_BYTES;
static const size_t T8P_OFF   = T3P_OFF;   // t3p dead before outp writes t8p

__device__ __forceinline__ void gl16(const f16* g, f16* l) {
  __builtin_amdgcn_global_load_lds((const __attribute__((address_space(1))) void*)g,
                                   (__attribute__((address_space(3))) void*)l, 16, 0, 0);
}

// ---------------------------------------------------------------- prep (xk, w-inner)
__global__ __launch_bounds__(256) void prep_kernel(const float* __restrict__ x,
                                                   f16* __restrict__ xk) {
  unsigned p = blockIdx.x * 256u + threadIdx.x;
  unsigned total = 3u * 4u * 128u * 82u * 32u;
  if (p >= total) return;
  unsigned wp   = p & 31u;
  unsigned row  = (p >> 5) % 82u;
  unsigned rest = p / (32u * 82u);
  unsigned c    = rest & 127u;
  unsigned rest2 = rest >> 7;
  unsigned n    = rest2 & 3u;
  unsigned kc   = rest2 >> 2;
  int hsrc = (int)row - 9;
  int wsrc = (int)(wp * 2u) + 2 * (int)kc - 2;
  f16x2 v; v.x = (f16)0.f; v.y = (f16)0.f;
  if (hsrc >= 0 && hsrc < 64 && wsrc >= 0 && wsrc < 64) {
    const float2* src = (const float2*)(x + (((size_t)(n * 128u + c) * 64u + (unsigned)hsrc) * 64u + (unsigned)wsrc));
    float2 xv = *src;
    v.x = (f16)(xv.x * 0.125f);
    v.y = (f16)(xv.y * 0.125f);
  }
  ((f16x2*)xk)[p] = v;
}

// ---------------------------------------------------------------- gram (LDS-staged, rki 0..10, split-K)
// grid 704 = n(4)*rki(11)*cseg(2)*ks(8); block 256 (4 waves 2x2), tile 64c x 128d, K-slice 512, 8 steps.
__global__ __launch_bounds__(256, 3) void gram_kernel(const f16* __restrict__ xk,
                                                      f16* __restrict__ t3p) {
  __shared__ f16 gl[2 * 12288];

  unsigned b    = blockIdx.x;
  unsigned ks   = b & 7u;
  unsigned cseg = (b >> 3) & 1u;
  unsigned rki  = (b >> 4) % 11u;
  unsigned n    = b / 176u;
  unsigned r    = rki / 3u;
  unsigned kc   = rki - r * 3u;

  unsigned tid  = threadIdx.x;
  unsigned wv   = tid >> 6;
  unsigned lane = tid & 63u;
  unsigned wy   = wv >> 1;
  unsigned wx   = wv & 1u;
  unsigned quad = lane >> 4;
  unsigned l16  = lane & 15u;
  unsigned rsl  = lane >> 3;
  unsigned seg  = (lane & 7u) ^ (rsl & 7u);

  unsigned h0 = ks * 8u;
  const f16* Ab = xk + (size_t)(kc * 4u + n) * 128u * XSTR + (size_t)(cseg * 64u) * XSTR
                + (h0 + 3u * r) * 64u + seg * 8u;
  const f16* Bb = xk + (size_t)(4u + n) * 128u * XSTR + (h0 + 9u) * 64u + seg * 8u;
  unsigned ar0 = wv * 16u;
  unsigned br0 = wv * 32u;

  f32x4 acc[2][4] = {};

#pragma unroll
  for (unsigned t = 0; t < 2u; t++)
    gl16(Ab + (size_t)(ar0 + t * 8u + rsl) * XSTR, &gl[(ar0 + t * 8u) * 64u]);
#pragma unroll
  for (unsigned t = 0; t < 4u; t++)
    gl16(Bb + (size_t)(br0 + t * 8u + rsl) * XSTR, &gl[4096u + (br0 + t * 8u) * 64u]);

  for (unsigned s = 0; s < 8u; s++) {
    __syncthreads();
    if (s < 7u) {
      f16* base = &gl[((s + 1u) & 1u) * 12288u];
      unsigned off = (s + 1u) * 64u;
#pragma unroll
      for (unsigned t = 0; t < 2u; t++)
        gl16(Ab + off + (size_t)(ar0 + t * 8u + rsl) * XSTR, base + (ar0 + t * 8u) * 64u);
#pragma unroll
      for (unsigned t = 0; t < 4u; t++)
        gl16(Bb + off + (size_t)(br0 + t * 8u + rsl) * XSTR, base + 4096u + (br0 + t * 8u) * 64u);
    }
    const f16* bufA = &gl[(s & 1u) * 12288u];
    const f16* bufB = bufA + 4096u;
#pragma unroll
    for (unsigned t2 = 0; t2 < 2u; t2++) {
      unsigned L = t2 * 4u + quad;
      f16x8 a[2], bb[4];
#pragma unroll
      for (int ms = 0; ms < 2; ms++) {
        unsigned rr = wy * 32u + (unsigned)ms * 16u + l16;
        a[ms] = *(const f16x8*)&bufA[rr * 64u + (L ^ (rr & 7u)) * 8u];
      }
#pragma unroll
      for (int ns = 0; ns < 4; ns++) {
        unsigned rb = wx * 64u + (unsigned)ns * 16u + l16;
        bb[ns] = *(const f16x8*)&bufB[rb * 64u + (L ^ (rb & 7u)) * 8u];
      }
#pragma unroll
      for (int ms = 0; ms < 2; ms++)
#pragma unroll
        for (int ns = 0; ns < 4; ns++)
          acc[ms][ns] = __builtin_amdgcn_mfma_f32_16x16x32_f16(a[ms], bb[ns], acc[ms][ns], 0, 0, 0);
    }
  }

  f16* tp = t3p + ((size_t)(ks * 4u + n) * 11u + rki) * 16384u;
#pragma unroll
  for (int ms = 0; ms < 2; ms++) {
#pragma unroll
    for (int ns = 0; ns < 4; ns++) {
      unsigned c0 = cseg * 64u + wy * 32u + (unsigned)ms * 16u + quad * 4u;
      unsigned d  = wx * 64u + (unsigned)ns * 16u + l16;
#pragma unroll
      for (int reg = 0; reg < 4; reg++)
        tp[(size_t)(c0 + (unsigned)reg) * 128u + d] = (f16)acc[ms][ns][reg];
    }
  }
}

// ---------------------------------------------------------------- ep: t6B = p6 * t3 (mirror for rk>=11)
// t6B fragment-packed: idx = (n*21+rk)*16384 + (c>>5)*4096 + (d>>4)*512 + ((c>>3)&3)*128 + (d&15)*8 + (c&7)
__global__ __launch_bounds__(256) void ep_kernel(const f16* __restrict__ t3p,
                                                 const float* __restrict__ p6,
                                                 f16* __restrict__ t6B) {
  unsigned idx = blockIdx.x * 256u + threadIdx.x;   // < 344064
  unsigned t   = idx >> 12;                          // n*21+rk
  unsigned rk  = t % 21u;
  unsigned n   = t / 21u;
  f16* tb = t6B + (size_t)t * 16384u;

  if (rk <= 10u) {
    unsigned d4 = idx & 31u;
    unsigned c  = (idx >> 5) & 127u;
    unsigned d0 = d4 * 4u;
    float s0 = 0.f, s1 = 0.f, s2 = 0.f, s3 = 0.f;
#pragma unroll
    for (unsigned ks = 0; ks < 8u; ks++) {
      f16x4 v = *(const f16x4*)(t3p + (((size_t)(ks * 4u + n) * 11u + rk) * 16384u + c * 128u + d0));
      s0 += (float)v[0]; s1 += (float)v[1]; s2 += (float)v[2]; s3 += (float)v[3];
    }
    const float* pp = p6 + ((size_t)c * 21u + rk) * 128u + d0;
    f16* ob = tb + (c >> 5) * 4096u + (d0 >> 4) * 512u + ((c >> 3) & 3u) * 128u + (d0 & 15u) * 8u + (c & 7u);
    ob[0]  = (f16)(s0 * pp[0]);
    ob[8]  = (f16)(s1 * pp[1]);
    ob[16] = (f16)(s2 * pp[2]);
    ob[24] = (f16)(s3 * pp[3]);
  } else {
    unsigned mrk = 20u - rk;          // t3[c,rk,d] = t3p_sum[mrk][d][c]
    unsigned c4 = idx & 31u;
    unsigned d  = (idx >> 5) & 127u;
    unsigned c0 = c4 * 4u;
    float s0 = 0.f, s1 = 0.f, s2 = 0.f, s3 = 0.f;
#pragma unroll
    for (unsigned ks = 0; ks < 8u; ks++) {
      f16x4 v = *(const f16x4*)(t3p + (((size_t)(ks * 4u + n) * 11u + mrk) * 16384u + d * 128u + c0));
      s0 += (float)v[0]; s1 += (float)v[1]; s2 += (float)v[2]; s3 += (float)v[3];
    }
    f16x4 o;
    o[0] = (f16)(s0 * p6[((size_t)(c0 + 0u) * 21u + rk) * 128u + d]);
    o[1] = (f16)(s1 * p6[((size_t)(c0 + 1u) * 21u + rk) * 128u + d]);
    o[2] = (f16)(s2 * p6[((size_t)(c0 + 2u) * 21u + rk) * 128u + d]);
    o[3] = (f16)(s3 * p6[((size_t)(c0 + 3u) * 21u + rk) * 128u + d]);
    *(f16x4*)(tb + (c0 >> 5) * 4096u + (d >> 4) * 512u + ((c0 >> 3) & 3u) * 128u + (d & 15u) * 8u + (c0 & 7u)) = o;
  }
}

// ---------------------------------------------------------------- outp (t8 split-K x4), 512-thread / 8-wave
// grid 1024 = n(4)*h(64)*g(4); block 512 (8 waves, 2(w) x 4(d)), tile 64w x 128d.
// 4 blocks/CU * 8 waves = 32 waves/CU (full occupancy); B-fragments read coalesced from t6B.
#define ALDS_STR 40
#define RT_STR   66
__global__ __launch_bounds__(512, 8) void outp_kernel(const f16* __restrict__ xk,
                                                      const float* __restrict__ p5,
                                                      const f16* __restrict__ t6B,
                                                      f16* __restrict__ t8p) {
  __shared__ float smem[8448];    // 33792 B; first 10240 B = 2 staging bufs, aliased as Rt later
  f16* Alds = (f16*)smem;

  unsigned b = blockIdx.x;
  unsigned g = b & 3u;
  unsigned h = (b >> 2) & 63u;
  unsigned n = b >> 8;

  unsigned tid  = threadIdx.x;           // 0..511
  unsigned wv   = tid >> 6;              // 0..7
  unsigned lane = tid & 63u;
  unsigned wy   = wv >> 2;               // 0..1  (w half)
  unsigned wx   = wv & 3u;               // 0..3  (d quarter)
  unsigned quad = lane >> 4;
  unsigned l16  = lane & 15u;
  unsigned wst  = tid & 63u;             // staging w
  unsigned g8   = tid >> 6;              // staging c-group (4 channels each)
  unsigned cth  = g * 32u + g8 * 4u;     // this thread's first channel

  const float* prow0 = p5 + (size_t)cth * (21u * 4096u) + h * 64u + wst;
  const f16* t6b = t6B + (size_t)n * 344064u + g * 4096u + (size_t)lane * 8u;

  f32x4 acc[2][2] = {};
  f16 xv[4]; float pv[4];
  f16x8 bfc[2];

  { // prefetch chunk 0 (rk=0 -> r=0, kc=0)
    const f16* xrow = xk + (((size_t)n * 128u + cth) * XROWS + h) * 64u + wst;
#pragma unroll
    for (int i = 0; i < 4; i++) { xv[i] = xrow[(size_t)i * XSTR]; pv[i] = prow0[(size_t)i * (21u * 4096u)]; }
#pragma unroll
    for (int ns = 0; ns < 2; ns++) bfc[ns] = *(const f16x8*)(t6b + (wx * 2u + (unsigned)ns) * 512u);
  }

  for (unsigned j = 0; j < 21u; j++) {
    f16* Ag = Alds + (j & 1u) * 2560u;
    {
      f16x4 av;
#pragma unroll
      for (int i = 0; i < 4; i++) av[i] = (f16)((float)xv[i] * (1.0f + pv[i]));
      *(f16x4*)&Ag[wst * ALDS_STR + g8 * 4u] = av;
    }
    __syncthreads();

    f16x8 bfn[2];
    if (j < 20u) {   // register prefetch of chunk j+1 (overlaps MFMA below)
      unsigned rk = j + 1u;
      unsigned rr = rk / 3u;
      unsigned kcc = rk - rr * 3u;
      const f16* xrow = xk + (((size_t)(kcc * 4u + n) * 128u + cth) * XROWS + (h + 3u * rr)) * 64u + wst;
      const float* prow = prow0 + rk * 4096u;
#pragma unroll
      for (int i = 0; i < 4; i++) { xv[i] = xrow[(size_t)i * XSTR]; pv[i] = prow[(size_t)i * (21u * 4096u)]; }
#pragma unroll
      for (int ns = 0; ns < 2; ns++) bfn[ns] = *(const f16x8*)(t6b + rk * 16384u + (wx * 2u + (unsigned)ns) * 512u);
    }

    f16x8 a[2];
#pragma unroll
    for (int ms = 0; ms < 2; ms++)
      a[ms] = *(const f16x8*)&Ag[(wy * 32u + (unsigned)ms * 16u + l16) * ALDS_STR + quad * 8u];
#pragma unroll
    for (int ms = 0; ms < 2; ms++)
#pragma unroll
      for (int ns = 0; ns < 2; ns++)
        acc[ms][ns] = __builtin_amdgcn_mfma_f32_16x16x32_f16(a[ms], bfc[ns], acc[ms][ns], 0, 0, 0);
#pragma unroll
    for (int ns = 0; ns < 2; ns++) bfc[ns] = bfn[ns];
  }

  // transpose via LDS for coalesced f16 partial stores: t8p[g][n][h][d][w]
  __syncthreads();
  float* Rt = smem;
#pragma unroll
  for (int ms = 0; ms < 2; ms++)
#pragma unroll
    for (int ns = 0; ns < 2; ns++) {
      unsigned w0 = wy * 32u + (unsigned)ms * 16u + quad * 4u;
      unsigned d  = wx * 32u + (unsigned)ns * 16u + l16;
#pragma unroll
      for (int reg = 0; reg < 4; reg++)
        Rt[d * RT_STR + w0 + (unsigned)reg] = acc[ms][ns][reg];
    }
  __syncthreads();
  f16* op = t8p + ((size_t)((g * 4u + n) * 64u + h)) * 8192u;
  {
    unsigned row = tid >> 2;             // 0..127 (d)
    unsigned w0  = (tid & 3u) * 16u;
    f16x8 o0, o1;
#pragma unroll
    for (int i = 0; i < 8; i++) {
      o0[i] = (f16)Rt[row * RT_STR + w0 + (unsigned)i];
      o1[i] = (f16)Rt[row * RT_STR + w0 + 8u + (unsigned)i];
    }
    *(f16x8*)(op + row * 64u + w0) = o0;
    *(f16x8*)(op + row * 64u + w0 + 8u) = o1;
  }
}

// ---------------------------------------------------------------- red: out = FS * sum_g(t8p)
__global__ __launch_bounds__(256) void red_kernel(const f16* __restrict__ t8p,
                                                  float* __restrict__ out) {
  unsigned idx = blockIdx.x * 256u + threadIdx.x;
  unsigned w0 = (idx & 7u) * 8u;
  unsigned h  = (idx >> 3) & 63u;
  unsigned d  = (idx >> 9) & 127u;
  unsigned n  = idx >> 16;
  const float FS = 0.15430334996209192f;  // 8 / sqrt(2688)
  float s[8] = {};
#pragma unroll
  for (unsigned g = 0; g < 4u; g++) {
    f16x8 v = *(const f16x8*)(t8p + ((size_t)((g * 4u + n) * 64u + h)) * 8192u + d * 64u + w0);
#pragma unroll
    for (int i = 0; i < 8; i++) s[i] += (float)v[i];
  }
  f32x4 o0, o1;
#pragma unroll
  for (int i = 0; i < 4; i++) { o0[i] = s[i] * FS; o1[i] = s[i + 4] * FS; }
  float* op = out + ((size_t)(n * 128u + d) * 64u + h) * 64u + w0;
  *(f32x4*)op = o0;
  *(f32x4*)(op + 4) = o1;
}

// ---------------------------------------------------------------- launch
extern "C" void kernel_launch(void* const* d_in, const int* in_sizes, int n_in,
                              void* d_out, int out_size, void* d_ws, size_t ws_size,
                              hipStream_t stream) {
  const float* x  = (const float*)d_in[0];
  const float* p5 = (const float*)d_in[1];
  const float* p6 = (const float*)d_in[2];
  float* out = (float*)d_out;
  f16* xk  = (f16*)((char*)d_ws);
  f16* t6B = (f16*)((char*)d_ws + T6T_OFF);
  f16* t3p = (f16*)((char*)d_ws + T3P_OFF);
  f16* t8p = (f16*)((char*)d_ws + T8P_OFF);   // aliases t3p (dead after ep)

  unsigned prep_blocks = (3u * 4u * 128u * 82u * 32u + 255u) / 256u;  // 15744
  hipLaunchKernelGGL(prep_kernel, dim3(prep_blocks), dim3(256), 0, stream, x, xk);
  hipLaunchKernelGGL(gram_kernel, dim3(704),  dim3(256), 0, stream, xk, t3p);
  hipLaunchKernelGGL(ep_kernel,   dim3(1344), dim3(256), 0, stream, t3p, p6, t6B);
  hipLaunchKernelGGL(outp_kernel, dim3(1024), dim3(512), 0, stream, xk, p5, t6B, t8p);
  hipLaunchKernelGGL(red_kernel,  dim3(1024), dim3(256), 0, stream, t8p, out);
}

// Round 3
// 144.410 us; speedup vs baseline: 1.1565x; 1.0342x over previous
//
#include <hip/hip_runtime.h>

typedef _Float16 f16;
typedef _Float16 f16x2 __attribute__((ext_vector_type(2)));
typedef _Float16 f16x4 __attribute__((ext_vector_type(4)));
typedef _Float16 f16x8 __attribute__((ext_vector_type(8)));
typedef float    f32x4 __attribute__((ext_vector_type(4)));

// Geometry:
//   x:   (4,128,64,64) f32     p5: (128,21,64,64) f32
//   p6:  (128,21,128)  f32     out:(4,128,64,64)  f32
// Workspace:
//   xk  [3][4][128][82][64] f16 = x*(1/8), pre-shifted per kc, zero-padded rows
//   t6B [4][21][4][8][4][16][8] f16 = p6 * t3, MFMA-fragment-packed:
//        idx(n,rk,g,dblk,quad,l16,i) -> value t6[n][c=g*32+quad*8+i][rk][d=dblk*16+l16]
//        outp stages the 8KB (n,rk,g) slice to LDS via global_load_lds
//   t3p [8][4][11][128][128] f16 = split-K Gram partials, rki 0..10 ONLY
//        (t3[c,rk,d] = t3[d,20-rk,c] exactly — lag symmetry; ep mirrors rk>=11)
//   t8p [4][4][64][128][64]  f16 = split-K out partials (g,n,h,d,w), ALIASES t3p
#define XROWS 82
#define XSTR  (XROWS * 64)
#define XK_ELEMS (3u * 4u * 128u * (unsigned)XSTR)
static const size_t T6T_OFF   = (size_t)XK_ELEMS * 2;                 // 16.12 MB
static const size_t T6T_BYTES = (size_t)4 * 128 * 2688 * 2;           // 2.75 MB
static const size_t T3P_OFF   = T6T_OFF + T6T_BYTES;
static const size_t T8P_OFF   = T3P_OFF;   // t3p dead before outp writes t8p

__device__ __forceinline__ void gl16(const f16* g, f16* l) {
  __builtin_amdgcn_global_load_lds((const __attribute__((address_space(1))) void*)g,
                                   (__attribute__((address_space(3))) void*)l, 16, 0, 0);
}

// ---------------------------------------------------------------- prep (xk, w-inner)
__global__ __launch_bounds__(256) void prep_kernel(const float* __restrict__ x,
                                                   f16* __restrict__ xk) {
  unsigned p = blockIdx.x * 256u + threadIdx.x;
  unsigned total = 3u * 4u * 128u * 82u * 32u;
  if (p >= total) return;
  unsigned wp   = p & 31u;
  unsigned row  = (p >> 5) % 82u;
  unsigned rest = p / (32u * 82u);
  unsigned c    = rest & 127u;
  unsigned rest2 = rest >> 7;
  unsigned n    = rest2 & 3u;
  unsigned kc   = rest2 >> 2;
  int hsrc = (int)row - 9;
  int wsrc = (int)(wp * 2u) + 2 * (int)kc - 2;
  f16x2 v; v.x = (f16)0.f; v.y = (f16)0.f;
  if (hsrc >= 0 && hsrc < 64 && wsrc >= 0 && wsrc < 64) {
    const float2* src = (const float2*)(x + (((size_t)(n * 128u + c) * 64u + (unsigned)hsrc) * 64u + (unsigned)wsrc));
    float2 xv = *src;
    v.x = (f16)(xv.x * 0.125f);
    v.y = (f16)(xv.y * 0.125f);
  }
  ((f16x2*)xk)[p] = v;
}

// ---------------------------------------------------------------- gram (LDS-staged, rki 0..10, split-K)
// grid 704 = n(4)*rki(11)*cseg(2)*ks(8); block 256 (4 waves 2x2), tile 64c x 128d, K-slice 512, 8 steps.
__global__ __launch_bounds__(256, 3) void gram_kernel(const f16* __restrict__ xk,
                                                      f16* __restrict__ t3p) {
  __shared__ f16 gl[2 * 12288];

  unsigned b    = blockIdx.x;
  unsigned ks   = b & 7u;
  unsigned cseg = (b >> 3) & 1u;
  unsigned rki  = (b >> 4) % 11u;
  unsigned n    = b / 176u;
  unsigned r    = rki / 3u;
  unsigned kc   = rki - r * 3u;

  unsigned tid  = threadIdx.x;
  unsigned wv   = tid >> 6;
  unsigned lane = tid & 63u;
  unsigned wy   = wv >> 1;
  unsigned wx   = wv & 1u;
  unsigned quad = lane >> 4;
  unsigned l16  = lane & 15u;
  unsigned rsl  = lane >> 3;
  unsigned seg  = (lane & 7u) ^ (rsl & 7u);

  unsigned h0 = ks * 8u;
  const f16* Ab = xk + (size_t)(kc * 4u + n) * 128u * XSTR + (size_t)(cseg * 64u) * XSTR
                + (h0 + 3u * r) * 64u + seg * 8u;
  const f16* Bb = xk + (size_t)(4u + n) * 128u * XSTR + (h0 + 9u) * 64u + seg * 8u;
  unsigned ar0 = wv * 16u;
  unsigned br0 = wv * 32u;

  f32x4 acc[2][4] = {};

#pragma unroll
  for (unsigned t = 0; t < 2u; t++)
    gl16(Ab + (size_t)(ar0 + t * 8u + rsl) * XSTR, &gl[(ar0 + t * 8u) * 64u]);
#pragma unroll
  for (unsigned t = 0; t < 4u; t++)
    gl16(Bb + (size_t)(br0 + t * 8u + rsl) * XSTR, &gl[4096u + (br0 + t * 8u) * 64u]);

  for (unsigned s = 0; s < 8u; s++) {
    __syncthreads();
    if (s < 7u) {
      f16* base = &gl[((s + 1u) & 1u) * 12288u];
      unsigned off = (s + 1u) * 64u;
#pragma unroll
      for (unsigned t = 0; t < 2u; t++)
        gl16(Ab + off + (size_t)(ar0 + t * 8u + rsl) * XSTR, base + (ar0 + t * 8u) * 64u);
#pragma unroll
      for (unsigned t = 0; t < 4u; t++)
        gl16(Bb + off + (size_t)(br0 + t * 8u + rsl) * XSTR, base + 4096u + (br0 + t * 8u) * 64u);
    }
    const f16* bufA = &gl[(s & 1u) * 12288u];
    const f16* bufB = bufA + 4096u;
#pragma unroll
    for (unsigned t2 = 0; t2 < 2u; t2++) {
      unsigned L = t2 * 4u + quad;
      f16x8 a[2], bb[4];
#pragma unroll
      for (int ms = 0; ms < 2; ms++) {
        unsigned rr = wy * 32u + (unsigned)ms * 16u + l16;
        a[ms] = *(const f16x8*)&bufA[rr * 64u + (L ^ (rr & 7u)) * 8u];
      }
#pragma unroll
      for (int ns = 0; ns < 4; ns++) {
        unsigned rb = wx * 64u + (unsigned)ns * 16u + l16;
        bb[ns] = *(const f16x8*)&bufB[rb * 64u + (L ^ (rb & 7u)) * 8u];
      }
#pragma unroll
      for (int ms = 0; ms < 2; ms++)
#pragma unroll
        for (int ns = 0; ns < 4; ns++)
          acc[ms][ns] = __builtin_amdgcn_mfma_f32_16x16x32_f16(a[ms], bb[ns], acc[ms][ns], 0, 0, 0);
    }
  }

  f16* tp = t3p + ((size_t)(ks * 4u + n) * 11u + rki) * 16384u;
#pragma unroll
  for (int ms = 0; ms < 2; ms++) {
#pragma unroll
    for (int ns = 0; ns < 4; ns++) {
      unsigned c0 = cseg * 64u + wy * 32u + (unsigned)ms * 16u + quad * 4u;
      unsigned d  = wx * 64u + (unsigned)ns * 16u + l16;
#pragma unroll
      for (int reg = 0; reg < 4; reg++)
        tp[(size_t)(c0 + (unsigned)reg) * 128u + d] = (f16)acc[ms][ns][reg];
    }
  }
}

// ---------------------------------------------------------------- ep: t6B = p6 * t3 (mirror for rk>=11)
// t6B fragment-packed: idx = (n*21+rk)*16384 + (c>>5)*4096 + (d>>4)*512 + ((c>>3)&3)*128 + (d&15)*8 + (c&7)
__global__ __launch_bounds__(256) void ep_kernel(const f16* __restrict__ t3p,
                                                 const float* __restrict__ p6,
                                                 f16* __restrict__ t6B) {
  unsigned idx = blockIdx.x * 256u + threadIdx.x;   // < 344064
  unsigned t   = idx >> 12;                          // n*21+rk
  unsigned rk  = t % 21u;
  unsigned n   = t / 21u;
  f16* tb = t6B + (size_t)t * 16384u;

  if (rk <= 10u) {
    unsigned d4 = idx & 31u;
    unsigned c  = (idx >> 5) & 127u;
    unsigned d0 = d4 * 4u;
    float s0 = 0.f, s1 = 0.f, s2 = 0.f, s3 = 0.f;
#pragma unroll
    for (unsigned ks = 0; ks < 8u; ks++) {
      f16x4 v = *(const f16x4*)(t3p + (((size_t)(ks * 4u + n) * 11u + rk) * 16384u + c * 128u + d0));
      s0 += (float)v[0]; s1 += (float)v[1]; s2 += (float)v[2]; s3 += (float)v[3];
    }
    const float* pp = p6 + ((size_t)c * 21u + rk) * 128u + d0;
    // four consecutive d at fixed c: d0..d0+3 share (d>>4) granule? No —
    // d0&15 in {0,4,8,12}, so all 4 stay in same dblk; stride in packed idx is 8.
    f16* ob = tb + (c >> 5) * 4096u + (d0 >> 4) * 512u + ((c >> 3) & 3u) * 128u + (d0 & 15u) * 8u + (c & 7u);
    ob[0]  = (f16)(s0 * pp[0]);
    ob[8]  = (f16)(s1 * pp[1]);
    ob[16] = (f16)(s2 * pp[2]);
    ob[24] = (f16)(s3 * pp[3]);
  } else {
    unsigned mrk = 20u - rk;          // t3[c,rk,d] = t3p_sum[mrk][d][c]
    unsigned c4 = idx & 31u;
    unsigned d  = (idx >> 5) & 127u;
    unsigned c0 = c4 * 4u;
    float s0 = 0.f, s1 = 0.f, s2 = 0.f, s3 = 0.f;
#pragma unroll
    for (unsigned ks = 0; ks < 8u; ks++) {
      f16x4 v = *(const f16x4*)(t3p + (((size_t)(ks * 4u + n) * 11u + mrk) * 16384u + d * 128u + c0));
      s0 += (float)v[0]; s1 += (float)v[1]; s2 += (float)v[2]; s3 += (float)v[3];
    }
    f16x4 o;
    o[0] = (f16)(s0 * p6[((size_t)(c0 + 0u) * 21u + rk) * 128u + d]);
    o[1] = (f16)(s1 * p6[((size_t)(c0 + 1u) * 21u + rk) * 128u + d]);
    o[2] = (f16)(s2 * p6[((size_t)(c0 + 2u) * 21u + rk) * 128u + d]);
    o[3] = (f16)(s3 * p6[((size_t)(c0 + 3u) * 21u + rk) * 128u + d]);
    // c0 = 4*c4 -> c0&7 in {0,4}; c0..c0+3 contiguous inside one 8-channel granule
    *(f16x4*)(tb + (c0 >> 5) * 4096u + (d >> 4) * 512u + ((c0 >> 3) & 3u) * 128u + (d & 15u) * 8u + (c0 & 7u)) = o;
  }
}

// ---------------------------------------------------------------- outp (t8 split-K x4), 512-thread / 8-wave
// grid 1024 = n(4)*h(64)*g(4); block 512 (8 waves, 2(w) x 4(d)), tile 64w x 128d.
// 4 blocks/CU * 8 waves = 32 waves/CU. B fragments staged to LDS via global_load_lds
// (dbuf, 8KB/iter, 1x16B DMA per thread); A tile XOR-swizzled (2-way max on store+read).
// Waves 0-3 stage A (8 channels/thread, one f16x8 store); waves 4-7 compute-only.
#define RT_STR   66
__global__ __launch_bounds__(512, 8) void outp_kernel(const f16* __restrict__ xk,
                                                      const float* __restrict__ p5,
                                                      const f16* __restrict__ t6B,
                                                      f16* __restrict__ t8p) {
  __shared__ float smem[8448];    // 33792 B; loop uses first 24576 B, Rt aliases all
  f16* sm16 = (f16*)smem;
  // f16 offsets: A bufs [0,2048),[2048,4096); B bufs [4096,8192),[8192,12288)

  unsigned b = blockIdx.x;
  unsigned g = b & 3u;
  unsigned h = (b >> 2) & 63u;
  unsigned n = b >> 8;

  unsigned tid  = threadIdx.x;           // 0..511
  unsigned wv   = tid >> 6;              // 0..7
  unsigned lane = tid & 63u;
  unsigned wy   = wv >> 2;               // 0..1  (w half)
  unsigned wx   = wv & 3u;               // 0..3  (d quarter)
  unsigned quad = lane >> 4;
  unsigned l16  = lane & 15u;
  unsigned wst  = tid & 63u;             // staging w
  bool     stg  = (tid < 256u);          // waves 0-3 stage A
  unsigned cg8  = tid >> 6;              // 0..3 when stg (granule: 8 channels)
  unsigned cth  = g * 32u + cg8 * 8u;

  const float* prow0 = p5 + (size_t)cth * (21u * 4096u) + h * 64u + wst;
  const f16* t6base = t6B + (size_t)n * 344064u + g * 4096u;   // + rk*16384 per rk

  f32x4 acc[2][2] = {};
  f16 xv[8]; float pv[8];

  { // prefetch chunk 0 (rk=0 -> r=0, kc=0)
    if (stg) {
      const f16* xrow = xk + (((size_t)n * 128u + cth) * XROWS + h) * 64u + wst;
#pragma unroll
      for (int i = 0; i < 8; i++) { xv[i] = xrow[(size_t)i * XSTR]; pv[i] = prow0[(size_t)i * (21u * 4096u)]; }
    }
    gl16(t6base + (size_t)tid * 8u, sm16 + 4096u + tid * 8u);   // B(0) -> buf 0
  }

  for (unsigned j = 0; j < 21u; j++) {
    f16* Ag = sm16 + (j & 1u) * 2048u;
    const f16* Bg = sm16 + 4096u + (j & 1u) * 4096u;
    if (stg) {
      f16x8 av;
#pragma unroll
      for (int i = 0; i < 8; i++) av[i] = (f16)((float)xv[i] * (1.0f + pv[i]));
      unsigned gr = ((wst & 1u) << 2) | cg8;
      *(f16x8*)&Ag[(wst >> 1) * 64u + (gr ^ ((wst >> 1) & 7u)) * 8u] = av;
    }
    __syncthreads();   // A(j) visible; B(j) DMA drained (vmcnt before barrier)

    if (j < 20u) {     // prefetch chunk j+1 (overlaps ds_read + MFMA below)
      unsigned rk = j + 1u;
      gl16(t6base + (size_t)rk * 16384u + tid * 8u,
           sm16 + 4096u + (rk & 1u) * 4096u + tid * 8u);
      if (stg) {
        unsigned rr = rk / 3u;
        unsigned kcc = rk - rr * 3u;
        const f16* xrow = xk + (((size_t)(kcc * 4u + n) * 128u + cth) * XROWS + (h + 3u * rr)) * 64u + wst;
        const float* prow = prow0 + rk * 4096u;
#pragma unroll
        for (int i = 0; i < 8; i++) { xv[i] = xrow[(size_t)i * XSTR]; pv[i] = prow[(size_t)i * (21u * 4096u)]; }
      }
    }

    f16x8 a[2], bfr[2];
#pragma unroll
    for (int ms = 0; ms < 2; ms++) {
      unsigned rr = wy * 32u + (unsigned)ms * 16u + l16;
      unsigned gr = ((rr & 1u) << 2) | quad;
      a[ms] = *(const f16x8*)&Ag[(rr >> 1) * 64u + (gr ^ ((rr >> 1) & 7u)) * 8u];
    }
#pragma unroll
    for (int ns = 0; ns < 2; ns++)
      bfr[ns] = *(const f16x8*)&Bg[(wx * 2u + (unsigned)ns) * 512u + lane * 8u];
#pragma unroll
    for (int ms = 0; ms < 2; ms++)
#pragma unroll
      for (int ns = 0; ns < 2; ns++)
        acc[ms][ns] = __builtin_amdgcn_mfma_f32_16x16x32_f16(a[ms], bfr[ns], acc[ms][ns], 0, 0, 0);
  }

  // transpose via LDS for coalesced f16 partial stores: t8p[g][n][h][d][w]
  __syncthreads();
  float* Rt = smem;
#pragma unroll
  for (int ms = 0; ms < 2; ms++)
#pragma unroll
    for (int ns = 0; ns < 2; ns++) {
      unsigned w0 = wy * 32u + (unsigned)ms * 16u + quad * 4u;
      unsigned d  = wx * 32u + (unsigned)ns * 16u + l16;
#pragma unroll
      for (int reg = 0; reg < 4; reg++)
        Rt[d * RT_STR + w0 + (unsigned)reg] = acc[ms][ns][reg];
    }
  __syncthreads();
  f16* op = t8p + ((size_t)((g * 4u + n) * 64u + h)) * 8192u;
  {
    unsigned row = tid >> 2;             // 0..127 (d)
    unsigned w0  = (tid & 3u) * 16u;
    f16x8 o0, o1;
#pragma unroll
    for (int i = 0; i < 8; i++) {
      o0[i] = (f16)Rt[row * RT_STR + w0 + (unsigned)i];
      o1[i] = (f16)Rt[row * RT_STR + w0 + 8u + (unsigned)i];
    }
    *(f16x8*)(op + row * 64u + w0) = o0;
    *(f16x8*)(op + row * 64u + w0 + 8u) = o1;
  }
}

// ---------------------------------------------------------------- red: out = FS * sum_g(t8p)
__global__ __launch_bounds__(256) void red_kernel(const f16* __restrict__ t8p,
                                                  float* __restrict__ out) {
  unsigned idx = blockIdx.x * 256u + threadIdx.x;
  unsigned w0 = (idx & 7u) * 8u;
  unsigned h  = (idx >> 3) & 63u;
  unsigned d  = (idx >> 9) & 127u;
  unsigned n  = idx >> 16;
  const float FS = 0.15430334996209192f;  // 8 / sqrt(2688)
  float s[8] = {};
#pragma unroll
  for (unsigned g = 0; g < 4u; g++) {
    f16x8 v = *(const f16x8*)(t8p + ((size_t)((g * 4u + n) * 64u + h)) * 8192u + d * 64u + w0);
#pragma unroll
    for (int i = 0; i < 8; i++) s[i] += (float)v[i];
  }
  f32x4 o0, o1;
#pragma unroll
  for (int i = 0; i < 4; i++) { o0[i] = s[i] * FS; o1[i] = s[i + 4] * FS; }
  float* op = out + ((size_t)(n * 128u + d) * 64u + h) * 64u + w0;
  *(f32x4*)op = o0;
  *(f32x4*)(op + 4) = o1;
}

// ---------------------------------------------------------------- launch
extern "C" void kernel_launch(void* const* d_in, const int* in_sizes, int n_in,
                              void* d_out, int out_size, void* d_ws, size_t ws_size,
                              hipStream_t stream) {
  const float* x  = (const float*)d_in[0];
  const float* p5 = (const float*)d_in[1];
  const float* p6 = (const float*)d_in[2];
  float* out = (float*)d_out;
  f16* xk  = (f16*)((char*)d_ws);
  f16* t6B = (f16*)((char*)d_ws + T6T_OFF);
  f16* t3p = (f16*)((char*)d_ws + T3P_OFF);
  f16* t8p = (f16*)((char*)d_ws + T8P_OFF);   // aliases t3p (dead after ep)

  unsigned prep_blocks = (3u * 4u * 128u * 82u * 32u + 255u) / 256u;  // 15744
  hipLaunchKernelGGL(prep_kernel, dim3(prep_blocks), dim3(256), 0, stream, x, xk);
  hipLaunchKernelGGL(gram_kernel, dim3(704),  dim3(256), 0, stream, xk, t3p);
  hipLaunchKernelGGL(ep_kernel,   dim3(1344), dim3(256), 0, stream, t3p, p6, t6B);
  hipLaunchKernelGGL(outp_kernel, dim3(1024), dim3(512), 0, stream, xk, p5, t6B, t8p);
  hipLaunchKernelGGL(red_kernel,  dim3(1024), dim3(256), 0, stream, t8p, out);
}